// Round 13
// baseline (195.468 us; speedup 1.0000x reference)
//
#include <hip/hip_runtime.h>

typedef __bf16 bf16_t;
typedef __bf16 bf16x8 __attribute__((ext_vector_type(8)));
typedef float  f32x4  __attribute__((ext_vector_type(4)));
typedef float  f32x16 __attribute__((ext_vector_type(16)));
typedef unsigned u32x4 __attribute__((ext_vector_type(4)));

#define DIMM  1024
#define NHEAD 16
#define HDIM  64
#define BATCH 4
#define SEQ   2048
#define MROWS (BATCH*SEQ)   // 8192

#define AQB   128           // q rows per attn block
#define AKV   64            // kv per tile
#define NP    (SEQ/AQB)     // 16 q-blocks
#define SKS   72            // LDS row stride (elems), 144B, 16B-aligned
#define LOG2E 1.44269504088896f

// attn job classes, longest-first. hh: 0/1 = split half, 2 = whole qblk.
__device__ const int d_qb[24] = {15,15,7,14,14,13,13,6,12,12,11,11,5,10,10,9,9,4,8,8,3,2,1,0};
__device__ const int d_hh[24] = { 0, 1,2, 0, 1, 0, 1,2, 0, 1, 0, 1,2, 0, 1,0,1,2,0,1,2,2,2,2};

__device__ __forceinline__ void gload_lds16(const bf16_t* g, bf16_t* l) {
  __builtin_amdgcn_global_load_lds(
      (const __attribute__((address_space(1))) void*)g,
      (__attribute__((address_space(3))) void*)l, 16, 0, 0);
}

__device__ __forceinline__ unsigned short f2bu(float f) {
  bf16_t b = (bf16_t)f;
  return __builtin_bit_cast(unsigned short, b);
}
__device__ __forceinline__ float bu2f(unsigned short u) {
  return __uint_as_float(((unsigned)u) << 16);
}
__device__ __forceinline__ unsigned packbf(float a, float b) {
  return (unsigned)f2bu(a) | ((unsigned)f2bu(b) << 16);
}
__device__ __forceinline__ float fexp2(float x) {   // v_exp_f32 = 2^x
  float r; asm("v_exp_f32 %0, %1" : "=v"(r) : "v"(x)); return r;
}

// ---------------- fp32 -> bf16 flat convert (4 elems/thread) ----------------
__global__ void k_convert(const float* __restrict__ in, bf16_t* __restrict__ out, int n4) {
  int i = blockIdx.x * blockDim.x + threadIdx.x;
  if (i >= n4) return;
  float4 v = reinterpret_cast<const float4*>(in)[i];
  ushort4 o;
  o.x = f2bu(v.x); o.y = f2bu(v.y); o.z = f2bu(v.z); o.w = f2bu(v.w);
  reinterpret_cast<ushort4*>(out)[i] = o;
}

// ------------- fp32 [R][C] -> bf16 [C][R] tiled transpose-convert -----------
__global__ void k_transpose_convert(const float* __restrict__ in, bf16_t* __restrict__ out,
                                    int R, int C) {
  __shared__ float tile[32][33];
  int cb = blockIdx.x * 32, rb = blockIdx.y * 32;
  int tx = threadIdx.x, ty = threadIdx.y;
  #pragma unroll
  for (int i = 0; i < 4; ++i)
    tile[ty + i*8][tx] = in[(size_t)(rb + ty + i*8) * C + cb + tx];
  __syncthreads();
  #pragma unroll
  for (int i = 0; i < 4; ++i)
    out[(size_t)(cb + ty + i*8) * R + rb + tx] = (bf16_t)tile[tx][ty + i*8];
}

// ---------------- RoPE cos/sin table [SEQ][32], fp64 trig ------------------
__global__ void k_rope_table(float* __restrict__ cosT, float* __restrict__ sinT) {
  int id = blockIdx.x * blockDim.x + threadIdx.x;
  if (id >= SEQ * 32) return;
  int t = id >> 5, i = id & 31;
  double ang = (double)t * pow(10000.0, -(double)i / 32.0);
  cosT[id] = (float)cos(ang);
  sinT[id] = (float)sin(ang);
}

// ---------- 256x256 8-phase bf16 GEMM, QKV projection (M=8192 N=3072 K=1024)
// 8-phase T2+T3+T4+T5 schedule (see R9). Epilogue is layout-aware:
//   bx<4 : Q -> rope + 0.125*log2e scale -> head layout [bh][t][d]
//   bx<8 : K -> rope -> head layout
//   else : V -> TRANSPOSED [bh][d][t], ushort4-packed stores.
// Rope pair exchange = __shfl_xor(val,1) (adjacent-lane DPP); bias pre-rope.
__global__ __launch_bounds__(512, 2) void k_gemm0(
    const bf16_t* __restrict__ A, const bf16_t* __restrict__ BT,
    const float* __restrict__ bias,
    bf16_t* __restrict__ q, bf16_t* __restrict__ k, bf16_t* __restrict__ vt,
    const float* __restrict__ cosT, const float* __restrict__ sinT)
{
  __shared__ bf16_t sA[2][2][128 * 64];   // [buf][khalf]
  __shared__ bf16_t sB[2][2][128 * 64];

  const int tid = threadIdx.x;
  const int w = tid >> 6;
  const int lane = tid & 63;
  const int wm = w >> 2, wn = w & 3;       // 2M x 4N waves
  const int l15 = lane & 15, l4 = lane >> 4;

  // bijective XCD swizzle (nwg = 384, multiple of 8)
  int nwg = gridDim.x * gridDim.y;
  int id  = blockIdx.y * gridDim.x + blockIdx.x;
  int cpx = nwg >> 3;
  int sid = (id & 7) * cpx + (id >> 3);
  int bx = sid % gridDim.x, by = sid / gridDim.x;
  const int rowA0 = by * 256, colB0 = bx * 256;

  f32x4 acc[8][4] = {};
  bf16x8 bf_[4];

  auto stage = [&](int tile, int part) {   // part: 0=A.k0 1=B.k0 2=A.k1 3=B.k1
    if (tile >= 16) return;
    const int kh = part >> 1;
    const bool isB = part & 1;
    const bf16_t* src = isB ? BT : A;
    const int r0 = isB ? colB0 : rowA0;
    bf16_t* dst = (isB ? &sB[0][0][0] : &sA[0][0][0]) + ((tile & 1) * 2 + kh) * (128 * 64);
    #pragma unroll
    for (int call = 0; call < 2; ++call) {
      int n = call * 512 + tid;
      int R = n >> 3, slot = n & 7;
      int sp = slot ^ (R & 7);
      int row = R * 2 + (sp >> 2);
      gload_lds16(src + (size_t)(r0 + row) * 1024 + tile * 64 + kh * 32 + (sp & 3) * 8,
                  dst + n * 8);
    }
  };

  auto rdA = [&](int bc, int kh, int mfa) -> bf16x8 {
    int row = wm * 128 + mfa * 16 + l15;
    int R = row >> 1;
    int slot = (((row & 1) << 2) | l4) ^ (R & 7);
    return *reinterpret_cast<const bf16x8*>(&sA[bc][kh][R * 64 + slot * 8]);
  };
  auto rdB = [&](int bc, int kh, int nf) -> bf16x8 {
    int row = wn * 64 + nf * 16 + l15;
    int R = row >> 1;
    int slot = (((row & 1) << 2) | l4) ^ (R & 7);
    return *reinterpret_cast<const bf16x8*>(&sB[bc][kh][R * 64 + slot * 8]);
  };

  auto phase = [&](int bc, int kh, int mh, int stile, int spart, int wait_n) {
    bf16x8 af[4];
    if (mh == 0) {
      #pragma unroll
      for (int nf = 0; nf < 4; ++nf) bf_[nf] = rdB(bc, kh, nf);
    }
    #pragma unroll
    for (int mf = 0; mf < 4; ++mf) af[mf] = rdA(bc, kh, mh * 4 + mf);
    stage(stile, spart);
    if (wait_n == 4)      asm volatile("s_waitcnt vmcnt(4)" ::: "memory");
    else if (wait_n == 0) asm volatile("s_waitcnt vmcnt(0)" ::: "memory");
    __builtin_amdgcn_s_barrier();
    __builtin_amdgcn_s_setprio(1);
    #pragma unroll
    for (int mf = 0; mf < 4; ++mf)
      #pragma unroll
      for (int nf = 0; nf < 4; ++nf)
        acc[mh * 4 + mf][nf] = __builtin_amdgcn_mfma_f32_16x16x32_bf16(
            af[mf], bf_[nf], acc[mh * 4 + mf][nf], 0, 0, 0);
    __builtin_amdgcn_s_setprio(0);
    __builtin_amdgcn_s_barrier();
  };

  // prologue: tile0 fully + tile1 k0-halves; wait all but newest 2 half-tiles
  stage(0, 0); stage(0, 1); stage(0, 2); stage(0, 3);
  stage(1, 0); stage(1, 1);
  asm volatile("s_waitcnt vmcnt(4)" ::: "memory");
  __builtin_amdgcn_s_barrier();

  for (int i = 0; i < 8; ++i) {
    const int t0 = 2 * i, t1 = 2 * i + 1;
    phase(0, 0, 0, t1,     2, -1);
    phase(0, 0, 1, t1,     3, -1);
    phase(0, 1, 0, t0 + 2, 0, -1);
    phase(0, 1, 1, t0 + 2, 1, (t0 + 2 < 16) ? 4 : 0);
    phase(1, 0, 0, t0 + 2, 2, -1);
    phase(1, 0, 1, t0 + 2, 3, -1);
    phase(1, 1, 0, t0 + 3, 0, -1);
    phase(1, 1, 1, t0 + 3, 1, (t0 + 3 < 16) ? 4 : 0);
  }

  // ---- epilogue ----
  const bool isV = (bx >= 8);
  const bool isQ = (bx < 4);
  const float qs = 0.125f * LOG2E;
  if (isV) {
    #pragma unroll
    for (int mfa = 0; mfa < 8; ++mfa) {
      #pragma unroll
      for (int nf = 0; nf < 4; ++nf) {
        int n = colB0 + wn * 64 + nf * 16 + l15;
        int h = (n >> 6) & 15, d = n & 63;
        float bs = bias[n];
        int m0 = rowA0 + wm * 128 + mfa * 16 + l4 * 4;
        int b = m0 >> 11, t = m0 & 2047;
        ushort4 pk;
        pk.x = f2bu(acc[mfa][nf][0] + bs);
        pk.y = f2bu(acc[mfa][nf][1] + bs);
        pk.z = f2bu(acc[mfa][nf][2] + bs);
        pk.w = f2bu(acc[mfa][nf][3] + bs);
        *reinterpret_cast<ushort4*>(
            vt + ((size_t)((b * NHEAD + h) * HDIM + d)) * SEQ + t) = pk;
      }
    }
  } else {
    bf16_t* dst = isQ ? q : k;
    #pragma unroll
    for (int mfa = 0; mfa < 8; ++mfa) {
      #pragma unroll
      for (int nf = 0; nf < 4; ++nf) {
        int n = colB0 + wn * 64 + nf * 16 + l15;
        int h = (n >> 6) & 15, d = n & 63;
        int i2 = d >> 1;
        float bs = bias[n];
        #pragma unroll
        for (int r = 0; r < 4; ++r) {
          int m = rowA0 + wm * 128 + mfa * 16 + l4 * 4 + r;
          int b = m >> 11, t = m & 2047;
          float val = acc[mfa][nf][r] + bs;
          float prt = __shfl_xor(val, 1);    // partner within the rope pair
          float c = cosT[(t << 5) + i2], s = sinT[(t << 5) + i2];
          float y = (d & 1) ? (val * c + prt * s) : (val * c - prt * s);
          if (isQ) y *= qs;                  // exp2-domain softmax scale
          dst[((size_t)(b * NHEAD + h) * SEQ + t) * HDIM + d] = (bf16_t)y;
        }
      }
    }
  }
}

// --------------- 128x128 bf16 GEMM (out-proj): fp32 out [M][N] -------------
__global__ __launch_bounds__(256) void k_gemm1(
    const bf16_t* __restrict__ A, const bf16_t* __restrict__ BT,
    const float* __restrict__ bias, float* __restrict__ outf, int M, int N, int K)
{
  __shared__ bf16_t sA[128 * 32];
  __shared__ bf16_t sB[128 * 32];
  const int tid = threadIdx.x;
  const int w = tid >> 6, lane = tid & 63;
  const int wr = w >> 1, wc = w & 1;
  const int l15 = lane & 15, l4 = lane >> 4;

  int nwg = gridDim.x * gridDim.y;
  int id  = blockIdx.y * gridDim.x + blockIdx.x;
  int cpx = nwg >> 3;
  int sid = (id & 7) * cpx + (id >> 3);
  int bx = sid % gridDim.x, by = sid / gridDim.x;

  const int rowA0 = by * 128;
  const int colB0 = bx * 128;

  f32x4 acc[4][4] = {};

  const int nkt = K >> 5;
  for (int kt = 0; kt < nkt; ++kt) {
    __syncthreads();
    #pragma unroll
    for (int i = 0; i < 2; ++i) {
      int c = i * 256 + w * 64 + lane;
      int row = c >> 2, k8 = (c & 3) * 8;
      gload_lds16(A  + (size_t)(rowA0 + row) * K + kt * 32 + k8, sA + (i * 256 + w * 64) * 8);
      gload_lds16(BT + (size_t)(colB0 + row) * K + kt * 32 + k8, sB + (i * 256 + w * 64) * 8);
    }
    asm volatile("s_waitcnt vmcnt(0)" ::: "memory");
    __syncthreads();
    bf16x8 af[4], bfr[4];
    #pragma unroll
    for (int mi = 0; mi < 4; ++mi)
      af[mi] = *reinterpret_cast<const bf16x8*>(sA + (wr * 64 + mi * 16 + l15) * 32 + l4 * 8);
    #pragma unroll
    for (int ni = 0; ni < 4; ++ni)
      bfr[ni] = *reinterpret_cast<const bf16x8*>(sB + (wc * 64 + ni * 16 + l15) * 32 + l4 * 8);
    #pragma unroll
    for (int mi = 0; mi < 4; ++mi)
      #pragma unroll
      for (int ni = 0; ni < 4; ++ni)
        acc[mi][ni] = __builtin_amdgcn_mfma_f32_16x16x32_bf16(af[mi], bfr[ni], acc[mi][ni], 0, 0, 0);
  }

  #pragma unroll
  for (int mi = 0; mi < 4; ++mi) {
    #pragma unroll
    for (int ni = 0; ni < 4; ++ni) {
      int n = colB0 + wc * 64 + ni * 16 + l15;
      float bs = bias[n];
      #pragma unroll
      for (int r = 0; r < 4; ++r) {
        int m = rowA0 + wr * 64 + mi * 16 + l4 * 4 + r;
        outf[(size_t)m * N + n] = acc[mi][ni][r] + bs;
      }
    }
  }
}

// ------------- causal flash attention: swapped-operand 32x32 ----------------
// KV-SPLIT (R12 lesson): makespan was bound by the longest (bh,qblk) chunk
// (32 tiles; VALUBusy 53% = 68/128 slot-utilization). qblk>=8 is split into
// two KV-halves (<=16 tiles) computed by independent jobs that write
// normalized bf16 partials + (m,l); qblk<=7 writes O directly. 1536 jobs,
// longest-first via class table -> backfill keeps 4 blocks/CU resident.
#define ATTN_BODY(CBUF, T)                                                     \
  do {                                                                         \
    const int t_ = (T);                                                        \
    if (t_ + 1 < t1) {                                                         \
      asm volatile("s_waitcnt vmcnt(0)" ::: "memory");                         \
      stage(CBUF ^ 1);                                                         \
      if (t_ + 2 < t1) issue(t_ + 2);                                          \
    }                                                                          \
    const bool masked = (t_ * AKV + AKV - 1 > qbase);                          \
    _Pragma("unroll")                                                          \
    for (int sub = 0; sub < 2; ++sub) {                                        \
      f32x16 sc = {};                                                          \
      __builtin_amdgcn_s_setprio(1);                                           \
      _Pragma("unroll")                                                        \
      for (int kt = 0; kt < 4; ++kt) {                                         \
        int krow = 32 * sub + l31;                                             \
        bf16x8 kf = *reinterpret_cast<const bf16x8*>(                          \
            &sK[CBUF][krow * SKS + (((2 * kt + hi) ^ (krow >> 3)) << 3)]);     \
        sc = __builtin_amdgcn_mfma_f32_32x32x16_bf16(kf, qf[kt], sc, 0, 0, 0); \
      }                                                                        \
      __builtin_amdgcn_s_setprio(0);                                           \
      float p[16];                                                             \
      const int qa = qbase + l31;                                              \
      const int kb0 = t_ * AKV + 32 * sub + 4 * hi;                            \
      _Pragma("unroll")                                                        \
      for (int r = 0; r < 16; ++r) {                                           \
        float s = sc[r];                                                       \
        if (masked) {                                                          \
          int kvi = kb0 + (r & 3) + 8 * (r >> 2);                              \
          if (kvi > qa) s = -1e30f;                                            \
        }                                                                      \
        p[r] = s;                                                              \
      }                                                                        \
      float m0 = fmaxf(fmaxf(p[0],  p[1]),  p[2]);                             \
      float m1 = fmaxf(fmaxf(p[3],  p[4]),  p[5]);                             \
      float m2 = fmaxf(fmaxf(p[6],  p[7]),  p[8]);                             \
      float m3 = fmaxf(fmaxf(p[9],  p[10]), p[11]);                            \
      float m4 = fmaxf(fmaxf(p[12], p[13]), p[14]);                            \
      float mt = fmaxf(fmaxf(fmaxf(m0, m1), fmaxf(m2, m3)), fmaxf(m4, p[15]));\
      mt = fmaxf(mt, __shfl_xor(mt, 32));                                      \
      if (!__all(mt <= mrun + 11.54f)) {                                       \
        float mnew = fmaxf(mrun, mt);                                          \
        float scl = fexp2(mrun - mnew);                                        \
        mrun = mnew;                                                           \
        lrun *= scl;                                                           \
        _Pragma("unroll")                                                      \
        for (int i = 0; i < 16; ++i) { accO[0][i] *= scl; accO[1][i] *= scl; } \
      }                                                                        \
      float rs = 0.f;                                                          \
      _Pragma("unroll")                                                        \
      for (int r = 0; r < 16; ++r) { p[r] = fexp2(p[r] - mrun); rs += p[r]; }  \
      lrun += rs + __shfl_xor(rs, 32);                                         \
      bf16x8 pf[2];                                                            \
      _Pragma("unroll")                                                        \
      for (int kt = 0; kt < 2; ++kt) {                                         \
        unsigned P01 = packbf(p[8*kt+0], p[8*kt+1]);                           \
        unsigned P23 = packbf(p[8*kt+2], p[8*kt+3]);                           \
        unsigned P45 = packbf(p[8*kt+4], p[8*kt+5]);                           \
        unsigned P67 = packbf(p[8*kt+6], p[8*kt+7]);                           \
        unsigned ra = __shfl_xor(hi == 0 ? P45 : P01, 32);                     \
        unsigned rb = __shfl_xor(hi == 0 ? P67 : P23, 32);                     \
        unsigned dw0 = hi == 0 ? P01 : ra;                                     \
        unsigned dw1 = hi == 0 ? P23 : rb;                                     \
        unsigned dw2 = hi == 0 ? ra : P45;                                     \
        unsigned dw3 = hi == 0 ? rb : P67;                                     \
        pf[kt] = __builtin_bit_cast(bf16x8, (u32x4){dw0, dw1, dw2, dw3});      \
      }                                                                        \
      __builtin_amdgcn_s_setprio(1);                                           \
      _Pragma("unroll")                                                        \
      for (int dt = 0; dt < 2; ++dt) {                                         \
        _Pragma("unroll")                                                      \
        for (int kt = 0; kt < 2; ++kt) {                                       \
          int vrow = 32 * dt + l31;                                            \
          bf16x8 vf = *reinterpret_cast<const bf16x8*>(                        \
              &sV[CBUF][vrow * SKS + (((4 * sub + 2 * kt + hi) ^ (vrow >> 3)) << 3)]); \
          accO[dt] = __builtin_amdgcn_mfma_f32_32x32x16_bf16(vf, pf[kt], accO[dt], 0, 0, 0); \
        }                                                                      \
      }                                                                        \
      __builtin_amdgcn_s_setprio(0);                                           \
    }                                                                          \
    asm volatile("s_waitcnt lgkmcnt(0)" ::: "memory");                         \
    __builtin_amdgcn_s_barrier();                                              \
    asm volatile("" ::: "memory");                                             \
  } while (0)

__global__ __launch_bounds__(256, 2) void k_attn(
    const bf16_t* __restrict__ Q, const bf16_t* __restrict__ Kb,
    const bf16_t* __restrict__ Vt, bf16_t* __restrict__ O,
    bf16_t* __restrict__ Opart, float* __restrict__ ml)
{
  __shared__ bf16_t sK[2][64 * SKS];
  __shared__ bf16_t sV[2][64 * SKS];   // V^T: [d][kv]

  const int tid = threadIdx.x;
  const int w = tid >> 6, lane = tid & 63;
  const int l31 = lane & 31, hi = lane >> 5;

  const int id = blockIdx.x;
  const int cls = id >> 6;           // 0..23, longest-first
  const int bh = id & 63;
  const int qblk = d_qb[cls];
  const int hh = d_hh[cls];          // 0/1 split half, 2 whole
  const int ntf = 2 * qblk + 2;
  const int t0 = (hh == 1) ? (ntf >> 1) : 0;
  const int t1 = (hh == 0) ? (ntf >> 1) : ntf;

  const size_t hbase = (size_t)bh * SEQ * HDIM;
  const int b = bh >> 4, h = bh & 15;
  const int srow = tid >> 3, sslot = tid & 7;

  const int qbase = qblk * AQB + 32 * w;

  bf16x8 qf[4];
  #pragma unroll
  for (int kt = 0; kt < 4; ++kt)
    qf[kt] = *reinterpret_cast<const bf16x8*>(
        Q + hbase + (size_t)(qbase + l31) * HDIM + kt * 16 + hi * 8);
  asm volatile("s_waitcnt vmcnt(0)" ::: "memory");
  asm volatile("" : "+v"(qf[0]), "+v"(qf[1]), "+v"(qf[2]), "+v"(qf[3]));

  u32x4 kr[2], vr[2];
  auto issue = [&](int t) {
    const bf16_t* kp = Kb + hbase + (size_t)(t * AKV + srow) * HDIM + sslot * 8;
    const bf16_t* vp = Vt + hbase + (size_t)srow * SEQ + t * AKV + sslot * 8;
    asm volatile("global_load_dwordx4 %0, %1, off" : "=v"(kr[0]) : "v"(kp));
    asm volatile("global_load_dwordx4 %0, %1, off" : "=v"(kr[1]) : "v"(kp + 32 * HDIM));
    asm volatile("global_load_dwordx4 %0, %1, off" : "=v"(vr[0]) : "v"(vp));
    asm volatile("global_load_dwordx4 %0, %1, off" : "=v"(vr[1]) : "v"(vp + 32 * SEQ));
  };
  auto stage = [&](int nb) {
    #pragma unroll
    for (int cc = 0; cc < 2; ++cc) {
      int row = srow + 32 * cc;                  // kv row for K, d row for V^T
      *reinterpret_cast<u32x4*>(&sK[nb][row * SKS + ((sslot ^ (row >> 3)) << 3)]) = kr[cc];
      *reinterpret_cast<u32x4*>(&sV[nb][row * SKS + ((sslot ^ (row >> 3)) << 3)]) = vr[cc];
    }
  };

  float mrun = -1e30f, lrun = 0.f;
  f32x16 accO[2] = {};

  issue(t0);
  asm volatile("s_waitcnt vmcnt(0)" ::: "memory");
  stage(0);
  if (t0 + 1 < t1) issue(t0 + 1);
  asm volatile("s_waitcnt lgkmcnt(0)" ::: "memory");
  __builtin_amdgcn_s_barrier();
  asm volatile("" ::: "memory");

  int t = t0;
  if ((t1 - t0) & 1) {
    ATTN_BODY(0, t); ++t;
    for (; t < t1; t += 2) { ATTN_BODY(1, t); ATTN_BODY(0, t + 1); }
  } else {
    for (; t < t1; t += 2) { ATTN_BODY(0, t); ATTN_BODY(1, t + 1); }
  }

  // epilogue: transpose O^T -> rows via per-wave LDS region aliased onto sK
  bf16_t* sOw = &sK[0][0] + w * (32 * SKS);
  float inv = 1.f / lrun;
  #pragma unroll
  for (int dt = 0; dt < 2; ++dt)
    #pragma unroll
    for (int r = 0; r < 16; ++r) {
      int d = 32 * dt + (r & 3) + 8 * (r >> 2) + 4 * hi;
      sOw[l31 * SKS + (d ^ ((l31 >> 3) << 3))] = (bf16_t)(accO[dt][r] * inv);
    }
  if (hh == 2) {
    #pragma unroll
    for (int i = 0; i < 4; ++i) {
      int qr = 8 * i + (lane >> 3);
      int ch = lane & 7;
      bf16x8 vvv = *reinterpret_cast<const bf16x8*>(
          &sOw[qr * SKS + ((ch ^ (qr >> 3)) << 3)]);
      *reinterpret_cast<bf16x8*>(
          O + ((size_t)(b * SEQ + qbase + qr)) * DIMM + h * HDIM + ch * 8) = vvv;
    }
  } else {
    const int pb = ((qblk - 8) * 2 + hh) * 64 + bh;
    #pragma unroll
    for (int i = 0; i < 4; ++i) {
      int qr = 8 * i + (lane >> 3);
      int ch = lane & 7;
      bf16x8 vvv = *reinterpret_cast<const bf16x8*>(
          &sOw[qr * SKS + ((ch ^ (qr >> 3)) << 3)]);
      *reinterpret_cast<bf16x8*>(
          Opart + ((size_t)pb * 128 + 32 * w + qr) * 64 + ch * 8) = vvv;
    }
    if (hi == 0) {
      size_t mi = ((size_t)pb * 128 + 32 * w + l31) * 2;
      ml[mi] = mrun; ml[mi + 1] = lrun;
    }
  }
}

// ---- merge kernel: combine two normalized halves (log2-domain m) ----------
__global__ __launch_bounds__(256) void k_merge(
    const bf16_t* __restrict__ Opart, const float* __restrict__ ml,
    bf16_t* __restrict__ O)
{
  int blk = blockIdx.x;            // 0..511 : (qblk-8)*64 + bh
  int qi = blk >> 6;
  int bh = blk & 63;
  int b = bh >> 4, h = bh & 15;
  int qblk = qi + 8;
  int base0 = (qi * 2 + 0) * 64 + bh;
  int base1 = (qi * 2 + 1) * 64 + bh;
  int q = threadIdx.x >> 1;
  int d0 = (threadIdx.x & 1) * 32;

  float m0 = ml[((size_t)base0 * 128 + q) * 2], l0 = ml[((size_t)base0 * 128 + q) * 2 + 1];
  float m1 = ml[((size_t)base1 * 128 + q) * 2], l1 = ml[((size_t)base1 * 128 + q) * 2 + 1];
  float m = fmaxf(m0, m1);
  float w0 = fexp2(m0 - m) * l0;
  float w1 = fexp2(m1 - m) * l1;
  float inv = 1.f / (w0 + w1);
  w0 *= inv; w1 *= inv;

  const bf16_t* p0 = Opart + ((size_t)base0 * 128 + q) * 64 + d0;
  const bf16_t* p1 = Opart + ((size_t)base1 * 128 + q) * 64 + d0;
  bf16_t* po = O + ((size_t)(b * SEQ + qblk * 128 + q)) * DIMM + h * HDIM + d0;
  #pragma unroll
  for (int i = 0; i < 4; ++i) {
    bf16x8 a = *reinterpret_cast<const bf16x8*>(p0 + i * 8);
    bf16x8 c = *reinterpret_cast<const bf16x8*>(p1 + i * 8);
    bf16x8 o;
    #pragma unroll
    for (int j = 0; j < 8; ++j)
      o[j] = (bf16_t)(w0 * (float)a[j] + w1 * (float)c[j]);
    *reinterpret_cast<bf16x8*>(po + i * 8) = o;
  }
}

// ---------------------------------------------------------------------------
extern "C" void kernel_launch(void* const* d_in, const int* in_sizes, int n_in,
                              void* d_out, int out_size, void* d_ws, size_t ws_size,
                              hipStream_t stream) {
  const float* x     = (const float*)d_in[0];
  // d_in[1] = mask (causal tril) — structure hardcoded
  const float* qkv_w = (const float*)d_in[2];
  const float* qkv_b = (const float*)d_in[3];
  const float* out_w = (const float*)d_in[4];
  const float* out_b = (const float*)d_in[5];
  float* out = (float*)d_out;

  char* ws = (char*)d_ws;
  size_t off = 0;
  auto alloc = [&](size_t bytes) {
    char* p = ws + off;
    off += (bytes + 255) & ~(size_t)255;
    return (void*)p;
  };
  bf16_t* Xb    = (bf16_t*)alloc((size_t)MROWS * DIMM * 2);   // reused as Opart after gemm0
  bf16_t* WqkvT = (bf16_t*)alloc((size_t)3 * DIMM * DIMM * 2);
  bf16_t* WoutT = (bf16_t*)alloc((size_t)DIMM * DIMM * 2);
  bf16_t* Qh    = (bf16_t*)alloc((size_t)64 * SEQ * HDIM * 2);
  bf16_t* Kh    = (bf16_t*)alloc((size_t)64 * SEQ * HDIM * 2);
  bf16_t* Vth   = (bf16_t*)alloc((size_t)64 * HDIM * SEQ * 2);  // V^T [bh][d][t]
  bf16_t* AO    = (bf16_t*)alloc((size_t)MROWS * DIMM * 2);
  float*  cosT  = (float*)alloc((size_t)SEQ * 32 * 4);
  float*  sinT  = (float*)alloc((size_t)SEQ * 32 * 4);
  float*  mlbuf = (float*)alloc((size_t)16 * 64 * 128 * 2 * 4);  // 1 MB
  bf16_t* Opart = Xb;   // 16.7 MB partials alias Xb (dead after gemm0)

  k_convert<<<(MROWS * DIMM / 4 + 255) / 256, 256, 0, stream>>>(x, Xb, MROWS * DIMM / 4);
  k_transpose_convert<<<dim3(3 * DIMM / 32, DIMM / 32), dim3(32, 8), 0, stream>>>(qkv_w, WqkvT, DIMM, 3 * DIMM);
  k_transpose_convert<<<dim3(DIMM / 32, DIMM / 32), dim3(32, 8), 0, stream>>>(out_w, WoutT, DIMM, DIMM);
  k_rope_table<<<(SEQ * 32 + 255) / 256, 256, 0, stream>>>(cosT, sinT);

  k_gemm0<<<dim3(3 * DIMM / 256, MROWS / 256), 512, 0, stream>>>(
      Xb, WqkvT, qkv_b, Qh, Kh, Vth, cosT, sinT);

  k_attn<<<dim3(24 * 64), 256, 0, stream>>>(Qh, Kh, Vth, AO, Opart, mlbuf);

  k_merge<<<dim3(512), 256, 0, stream>>>(Opart, mlbuf, AO);

  k_gemm1<<<dim3(DIMM / 128, MROWS / 128), 256, 0, stream>>>(
      AO, WoutT, out_b, out, MROWS, DIMM, DIMM);
}

// Round 14
// 192.167 us; speedup vs baseline: 1.0172x; 1.0172x over previous
//
#include <hip/hip_runtime.h>

typedef __bf16 bf16_t;
typedef __bf16 bf16x8 __attribute__((ext_vector_type(8)));
typedef float  f32x4  __attribute__((ext_vector_type(4)));
typedef float  f32x16 __attribute__((ext_vector_type(16)));
typedef unsigned u32x4 __attribute__((ext_vector_type(4)));

#define DIMM  1024
#define NHEAD 16
#define HDIM  64
#define BATCH 4
#define SEQ   2048
#define MROWS (BATCH*SEQ)   // 8192

#define AQB   128           // q rows per attn block
#define AKV   64            // kv per tile
#define NP    (SEQ/AQB)     // 16 q-blocks
#define SKS   72            // LDS row stride (elems), 144B, 16B-aligned
#define LOG2E 1.44269504088896f

// attn job classes, longest-first. hh: 0/1 = split half, 2 = whole qblk.
__device__ const int d_qb[24] = {15,15,7,14,14,13,13,6,12,12,11,11,5,10,10,9,9,4,8,8,3,2,1,0};
__device__ const int d_hh[24] = { 0, 1,2, 0, 1, 0, 1,2, 0, 1, 0, 1,2, 0, 1,0,1,2,0,1,2,2,2,2};

__device__ __forceinline__ void gload_lds16(const bf16_t* g, bf16_t* l) {
  __builtin_amdgcn_global_load_lds(
      (const __attribute__((address_space(1))) void*)g,
      (__attribute__((address_space(3))) void*)l, 16, 0, 0);
}

__device__ __forceinline__ unsigned short f2bu(float f) {
  bf16_t b = (bf16_t)f;
  return __builtin_bit_cast(unsigned short, b);
}
__device__ __forceinline__ float bu2f(unsigned short u) {
  return __uint_as_float(((unsigned)u) << 16);
}
__device__ __forceinline__ unsigned packbf(float a, float b) {
  return (unsigned)f2bu(a) | ((unsigned)f2bu(b) << 16);
}
__device__ __forceinline__ float fexp2(float x) {   // v_exp_f32 = 2^x
  float r; asm("v_exp_f32 %0, %1" : "=v"(r) : "v"(x)); return r;
}

// ---------------- fp32 -> bf16 flat convert (4 elems/thread) ----------------
__global__ void k_convert(const float* __restrict__ in, bf16_t* __restrict__ out, int n4) {
  int i = blockIdx.x * blockDim.x + threadIdx.x;
  if (i >= n4) return;
  float4 v = reinterpret_cast<const float4*>(in)[i];
  ushort4 o;
  o.x = f2bu(v.x); o.y = f2bu(v.y); o.z = f2bu(v.z); o.w = f2bu(v.w);
  reinterpret_cast<ushort4*>(out)[i] = o;
}

// ------------- fp32 [R][C] -> bf16 [C][R] tiled transpose-convert -----------
__global__ void k_transpose_convert(const float* __restrict__ in, bf16_t* __restrict__ out,
                                    int R, int C) {
  __shared__ float tile[32][33];
  int cb = blockIdx.x * 32, rb = blockIdx.y * 32;
  int tx = threadIdx.x, ty = threadIdx.y;
  #pragma unroll
  for (int i = 0; i < 4; ++i)
    tile[ty + i*8][tx] = in[(size_t)(rb + ty + i*8) * C + cb + tx];
  __syncthreads();
  #pragma unroll
  for (int i = 0; i < 4; ++i)
    out[(size_t)(cb + ty + i*8) * R + rb + tx] = (bf16_t)tile[tx][ty + i*8];
}

// ---------------- RoPE cos/sin table [SEQ][32], fp64 trig ------------------
__global__ void k_rope_table(float* __restrict__ cosT, float* __restrict__ sinT) {
  int id = blockIdx.x * blockDim.x + threadIdx.x;
  if (id >= SEQ * 32) return;
  int t = id >> 5, i = id & 31;
  double ang = (double)t * pow(10000.0, -(double)i / 32.0);
  cosT[id] = (float)cos(ang);
  sinT[id] = (float)sin(ang);
}

// ---------- 256x256 8-phase bf16 GEMM, QKV projection (M=8192 N=3072 K=1024)
// 8-phase T2+T3+T4+T5 schedule (see R9). Epilogue is layout-aware:
//   bx<4 : Q -> rope + 0.125*log2e scale -> head layout [bh][t][d]
//   bx<8 : K -> rope -> head layout
//   else : V -> TRANSPOSED [bh][d][t], ushort4-packed stores.
// Rope pair exchange = __shfl_xor(val,1) (adjacent-lane DPP); bias pre-rope.
__global__ __launch_bounds__(512, 2) void k_gemm0(
    const bf16_t* __restrict__ A, const bf16_t* __restrict__ BT,
    const float* __restrict__ bias,
    bf16_t* __restrict__ q, bf16_t* __restrict__ k, bf16_t* __restrict__ vt,
    const float* __restrict__ cosT, const float* __restrict__ sinT)
{
  __shared__ bf16_t sA[2][2][128 * 64];   // [buf][khalf]
  __shared__ bf16_t sB[2][2][128 * 64];

  const int tid = threadIdx.x;
  const int w = tid >> 6;
  const int lane = tid & 63;
  const int wm = w >> 2, wn = w & 3;       // 2M x 4N waves
  const int l15 = lane & 15, l4 = lane >> 4;

  // bijective XCD swizzle (nwg = 384, multiple of 8)
  int nwg = gridDim.x * gridDim.y;
  int id  = blockIdx.y * gridDim.x + blockIdx.x;
  int cpx = nwg >> 3;
  int sid = (id & 7) * cpx + (id >> 3);
  int bx = sid % gridDim.x, by = sid / gridDim.x;
  const int rowA0 = by * 256, colB0 = bx * 256;

  f32x4 acc[8][4] = {};
  bf16x8 bf_[4];

  auto stage = [&](int tile, int part) {   // part: 0=A.k0 1=B.k0 2=A.k1 3=B.k1
    if (tile >= 16) return;
    const int kh = part >> 1;
    const bool isB = part & 1;
    const bf16_t* src = isB ? BT : A;
    const int r0 = isB ? colB0 : rowA0;
    bf16_t* dst = (isB ? &sB[0][0][0] : &sA[0][0][0]) + ((tile & 1) * 2 + kh) * (128 * 64);
    #pragma unroll
    for (int call = 0; call < 2; ++call) {
      int n = call * 512 + tid;
      int R = n >> 3, slot = n & 7;
      int sp = slot ^ (R & 7);
      int row = R * 2 + (sp >> 2);
      gload_lds16(src + (size_t)(r0 + row) * 1024 + tile * 64 + kh * 32 + (sp & 3) * 8,
                  dst + n * 8);
    }
  };

  auto rdA = [&](int bc, int kh, int mfa) -> bf16x8 {
    int row = wm * 128 + mfa * 16 + l15;
    int R = row >> 1;
    int slot = (((row & 1) << 2) | l4) ^ (R & 7);
    return *reinterpret_cast<const bf16x8*>(&sA[bc][kh][R * 64 + slot * 8]);
  };
  auto rdB = [&](int bc, int kh, int nf) -> bf16x8 {
    int row = wn * 64 + nf * 16 + l15;
    int R = row >> 1;
    int slot = (((row & 1) << 2) | l4) ^ (R & 7);
    return *reinterpret_cast<const bf16x8*>(&sB[bc][kh][R * 64 + slot * 8]);
  };

  auto phase = [&](int bc, int kh, int mh, int stile, int spart, int wait_n) {
    bf16x8 af[4];
    if (mh == 0) {
      #pragma unroll
      for (int nf = 0; nf < 4; ++nf) bf_[nf] = rdB(bc, kh, nf);
    }
    #pragma unroll
    for (int mf = 0; mf < 4; ++mf) af[mf] = rdA(bc, kh, mh * 4 + mf);
    stage(stile, spart);
    if (wait_n == 4)      asm volatile("s_waitcnt vmcnt(4)" ::: "memory");
    else if (wait_n == 0) asm volatile("s_waitcnt vmcnt(0)" ::: "memory");
    __builtin_amdgcn_s_barrier();
    __builtin_amdgcn_s_setprio(1);
    #pragma unroll
    for (int mf = 0; mf < 4; ++mf)
      #pragma unroll
      for (int nf = 0; nf < 4; ++nf)
        acc[mh * 4 + mf][nf] = __builtin_amdgcn_mfma_f32_16x16x32_bf16(
            af[mf], bf_[nf], acc[mh * 4 + mf][nf], 0, 0, 0);
    __builtin_amdgcn_s_setprio(0);
    __builtin_amdgcn_s_barrier();
  };

  // prologue: tile0 fully + tile1 k0-halves; wait all but newest 2 half-tiles
  stage(0, 0); stage(0, 1); stage(0, 2); stage(0, 3);
  stage(1, 0); stage(1, 1);
  asm volatile("s_waitcnt vmcnt(4)" ::: "memory");
  __builtin_amdgcn_s_barrier();

  for (int i = 0; i < 8; ++i) {
    const int t0 = 2 * i, t1 = 2 * i + 1;
    phase(0, 0, 0, t1,     2, -1);
    phase(0, 0, 1, t1,     3, -1);
    phase(0, 1, 0, t0 + 2, 0, -1);
    phase(0, 1, 1, t0 + 2, 1, (t0 + 2 < 16) ? 4 : 0);
    phase(1, 0, 0, t0 + 2, 2, -1);
    phase(1, 0, 1, t0 + 2, 3, -1);
    phase(1, 1, 0, t0 + 3, 0, -1);
    phase(1, 1, 1, t0 + 3, 1, (t0 + 3 < 16) ? 4 : 0);
  }

  // ---- epilogue ----
  const bool isV = (bx >= 8);
  const bool isQ = (bx < 4);
  const float qs = 0.125f * LOG2E;
  if (isV) {
    #pragma unroll
    for (int mfa = 0; mfa < 8; ++mfa) {
      #pragma unroll
      for (int nf = 0; nf < 4; ++nf) {
        int n = colB0 + wn * 64 + nf * 16 + l15;
        int h = (n >> 6) & 15, d = n & 63;
        float bs = bias[n];
        int m0 = rowA0 + wm * 128 + mfa * 16 + l4 * 4;
        int b = m0 >> 11, t = m0 & 2047;
        ushort4 pk;
        pk.x = f2bu(acc[mfa][nf][0] + bs);
        pk.y = f2bu(acc[mfa][nf][1] + bs);
        pk.z = f2bu(acc[mfa][nf][2] + bs);
        pk.w = f2bu(acc[mfa][nf][3] + bs);
        *reinterpret_cast<ushort4*>(
            vt + ((size_t)((b * NHEAD + h) * HDIM + d)) * SEQ + t) = pk;
      }
    }
  } else {
    bf16_t* dst = isQ ? q : k;
    #pragma unroll
    for (int mfa = 0; mfa < 8; ++mfa) {
      #pragma unroll
      for (int nf = 0; nf < 4; ++nf) {
        int n = colB0 + wn * 64 + nf * 16 + l15;
        int h = (n >> 6) & 15, d = n & 63;
        int i2 = d >> 1;
        float bs = bias[n];
        #pragma unroll
        for (int r = 0; r < 4; ++r) {
          int m = rowA0 + wm * 128 + mfa * 16 + l4 * 4 + r;
          int b = m >> 11, t = m & 2047;
          float val = acc[mfa][nf][r] + bs;
          float prt = __shfl_xor(val, 1);    // partner within the rope pair
          float c = cosT[(t << 5) + i2], s = sinT[(t << 5) + i2];
          float y = (d & 1) ? (val * c + prt * s) : (val * c - prt * s);
          if (isQ) y *= qs;                  // exp2-domain softmax scale
          dst[((size_t)(b * NHEAD + h) * SEQ + t) * HDIM + d] = (bf16_t)y;
        }
      }
    }
  }
}

// --------------- 128x128 bf16 GEMM (out-proj): fp32 out [M][N] -------------
__global__ __launch_bounds__(256) void k_gemm1(
    const bf16_t* __restrict__ A, const bf16_t* __restrict__ BT,
    const float* __restrict__ bias, float* __restrict__ outf, int M, int N, int K)
{
  __shared__ bf16_t sA[128 * 32];
  __shared__ bf16_t sB[128 * 32];
  const int tid = threadIdx.x;
  const int w = tid >> 6, lane = tid & 63;
  const int wr = w >> 1, wc = w & 1;
  const int l15 = lane & 15, l4 = lane >> 4;

  int nwg = gridDim.x * gridDim.y;
  int id  = blockIdx.y * gridDim.x + blockIdx.x;
  int cpx = nwg >> 3;
  int sid = (id & 7) * cpx + (id >> 3);
  int bx = sid % gridDim.x, by = sid / gridDim.x;

  const int rowA0 = by * 128;
  const int colB0 = bx * 128;

  f32x4 acc[4][4] = {};

  const int nkt = K >> 5;
  for (int kt = 0; kt < nkt; ++kt) {
    __syncthreads();
    #pragma unroll
    for (int i = 0; i < 2; ++i) {
      int c = i * 256 + w * 64 + lane;
      int row = c >> 2, k8 = (c & 3) * 8;
      gload_lds16(A  + (size_t)(rowA0 + row) * K + kt * 32 + k8, sA + (i * 256 + w * 64) * 8);
      gload_lds16(BT + (size_t)(colB0 + row) * K + kt * 32 + k8, sB + (i * 256 + w * 64) * 8);
    }
    asm volatile("s_waitcnt vmcnt(0)" ::: "memory");
    __syncthreads();
    bf16x8 af[4], bfr[4];
    #pragma unroll
    for (int mi = 0; mi < 4; ++mi)
      af[mi] = *reinterpret_cast<const bf16x8*>(sA + (wr * 64 + mi * 16 + l15) * 32 + l4 * 8);
    #pragma unroll
    for (int ni = 0; ni < 4; ++ni)
      bfr[ni] = *reinterpret_cast<const bf16x8*>(sB + (wc * 64 + ni * 16 + l15) * 32 + l4 * 8);
    #pragma unroll
    for (int mi = 0; mi < 4; ++mi)
      #pragma unroll
      for (int ni = 0; ni < 4; ++ni)
        acc[mi][ni] = __builtin_amdgcn_mfma_f32_16x16x32_bf16(af[mi], bfr[ni], acc[mi][ni], 0, 0, 0);
  }

  #pragma unroll
  for (int mi = 0; mi < 4; ++mi) {
    #pragma unroll
    for (int ni = 0; ni < 4; ++ni) {
      int n = colB0 + wc * 64 + ni * 16 + l15;
      float bs = bias[n];
      #pragma unroll
      for (int r = 0; r < 4; ++r) {
        int m = rowA0 + wr * 64 + mi * 16 + l4 * 4 + r;
        outf[(size_t)m * N + n] = acc[mi][ni][r] + bs;
      }
    }
  }
}

// ------------- causal flash attention: swapped-operand 32x32 ----------------
// R13 lesson: attn is bound by the per-tile serial chain, not makespan.
// This round MERGES the two 32-kv subs into one 64-kv softmax pass:
// 8 batched QK MFMAs (2 indep chains), ONE 31-op max tree + ONE cross-half
// shfl (was 2), 32 batched exp2, and lrun cross-half reduce DEFERRED to the
// job end (per-lane partials are per-q-column -> mergeable once).
#define ATTN_BODY(CBUF, T)                                                     \
  do {                                                                         \
    const int t_ = (T);                                                        \
    if (t_ + 1 < t1) {                                                         \
      asm volatile("s_waitcnt vmcnt(0)" ::: "memory");                         \
      stage(CBUF ^ 1);                                                         \
      if (t_ + 2 < t1) issue(t_ + 2);                                          \
    }                                                                          \
    const bool masked = (t_ * AKV + AKV - 1 > qbase);                          \
    f32x16 s0 = {}, s1 = {};                                                   \
    __builtin_amdgcn_s_setprio(1);                                             \
    _Pragma("unroll")                                                          \
    for (int kt = 0; kt < 4; ++kt) {                                           \
      bf16x8 kf0 = *reinterpret_cast<const bf16x8*>(                           \
          &sK[CBUF][l31 * SKS + (((2 * kt + hi) ^ (l31 >> 3)) << 3)]);         \
      s0 = __builtin_amdgcn_mfma_f32_32x32x16_bf16(kf0, qf[kt], s0, 0, 0, 0);  \
    }                                                                          \
    _Pragma("unroll")                                                          \
    for (int kt = 0; kt < 4; ++kt) {                                           \
      int kr1 = 32 + l31;                                                      \
      bf16x8 kf1 = *reinterpret_cast<const bf16x8*>(                           \
          &sK[CBUF][kr1 * SKS + (((2 * kt + hi) ^ (kr1 >> 3)) << 3)]);         \
      s1 = __builtin_amdgcn_mfma_f32_32x32x16_bf16(kf1, qf[kt], s1, 0, 0, 0);  \
    }                                                                          \
    __builtin_amdgcn_s_setprio(0);                                             \
    const int qa = qbase + l31;                                                \
    const int kb0 = t_ * AKV + 4 * hi;                                         \
    if (masked) {                                                              \
      _Pragma("unroll")                                                        \
      for (int r = 0; r < 16; ++r) {                                           \
        int kvi = kb0 + (r & 3) + 8 * (r >> 2);                                \
        if (kvi > qa) s0[r] = -1e30f;                                          \
        if (kvi + 32 > qa) s1[r] = -1e30f;                                     \
      }                                                                        \
    }                                                                          \
    float mm[16];                                                              \
    _Pragma("unroll")                                                          \
    for (int r = 0; r < 16; ++r) mm[r] = fmaxf(s0[r], s1[r]);                  \
    float m0_ = fmaxf(fmaxf(mm[0],  mm[1]),  mm[2]);                           \
    float m1_ = fmaxf(fmaxf(mm[3],  mm[4]),  mm[5]);                           \
    float m2_ = fmaxf(fmaxf(mm[6],  mm[7]),  mm[8]);                           \
    float m3_ = fmaxf(fmaxf(mm[9],  mm[10]), mm[11]);                          \
    float m4_ = fmaxf(fmaxf(mm[12], mm[13]), mm[14]);                          \
    float mt = fmaxf(fmaxf(fmaxf(m0_, m1_), fmaxf(m2_, m3_)), fmaxf(m4_, mm[15])); \
    mt = fmaxf(mt, __shfl_xor(mt, 32));                                        \
    if (!__all(mt <= mrun + 11.54f)) {                                         \
      float mnew = fmaxf(mrun, mt);                                            \
      float scl = fexp2(mrun - mnew);                                          \
      mrun = mnew;                                                             \
      lrun *= scl;                                                             \
      _Pragma("unroll")                                                        \
      for (int i = 0; i < 16; ++i) { accO[0][i] *= scl; accO[1][i] *= scl; }   \
    }                                                                          \
    float rs = 0.f;                                                            \
    _Pragma("unroll")                                                          \
    for (int r = 0; r < 16; ++r) { s0[r] = fexp2(s0[r] - mrun); rs += s0[r]; } \
    _Pragma("unroll")                                                          \
    for (int r = 0; r < 16; ++r) { s1[r] = fexp2(s1[r] - mrun); rs += s1[r]; } \
    lrun += rs;   /* per-lane partial; cross-half merged at job end */         \
    bf16x8 pf[4];                                                              \
    _Pragma("unroll")                                                          \
    for (int ktt = 0; ktt < 4; ++ktt) {                                        \
      const int bb = 8 * (ktt & 1);                                            \
      unsigned P01, P23, P45, P67;                                             \
      if (ktt < 2) {                                                           \
        P01 = packbf(s0[bb+0], s0[bb+1]); P23 = packbf(s0[bb+2], s0[bb+3]);    \
        P45 = packbf(s0[bb+4], s0[bb+5]); P67 = packbf(s0[bb+6], s0[bb+7]);    \
      } else {                                                                 \
        P01 = packbf(s1[bb+0], s1[bb+1]); P23 = packbf(s1[bb+2], s1[bb+3]);    \
        P45 = packbf(s1[bb+4], s1[bb+5]); P67 = packbf(s1[bb+6], s1[bb+7]);    \
      }                                                                        \
      unsigned ra = __shfl_xor(hi == 0 ? P45 : P01, 32);                       \
      unsigned rb = __shfl_xor(hi == 0 ? P67 : P23, 32);                       \
      unsigned dw0 = hi == 0 ? P01 : ra;                                       \
      unsigned dw1 = hi == 0 ? P23 : rb;                                       \
      unsigned dw2 = hi == 0 ? ra : P45;                                       \
      unsigned dw3 = hi == 0 ? rb : P67;                                       \
      pf[ktt] = __builtin_bit_cast(bf16x8, (u32x4){dw0, dw1, dw2, dw3});       \
    }                                                                          \
    __builtin_amdgcn_s_setprio(1);                                             \
    _Pragma("unroll")                                                          \
    for (int dt = 0; dt < 2; ++dt) {                                           \
      _Pragma("unroll")                                                        \
      for (int ktt = 0; ktt < 4; ++ktt) {                                      \
        int vrow = 32 * dt + l31;                                              \
        int slot = (4 * (ktt >> 1) + 2 * (ktt & 1) + hi) ^ (vrow >> 3);        \
        bf16x8 vf = *reinterpret_cast<const bf16x8*>(                          \
            &sV[CBUF][vrow * SKS + (slot << 3)]);                              \
        accO[dt] = __builtin_amdgcn_mfma_f32_32x32x16_bf16(vf, pf[ktt], accO[dt], 0, 0, 0); \
      }                                                                        \
    }                                                                          \
    __builtin_amdgcn_s_setprio(0);                                             \
    asm volatile("s_waitcnt lgkmcnt(0)" ::: "memory");                         \
    __builtin_amdgcn_s_barrier();                                              \
    asm volatile("" ::: "memory");                                             \
  } while (0)

__global__ __launch_bounds__(256, 2) void k_attn(
    const bf16_t* __restrict__ Q, const bf16_t* __restrict__ Kb,
    const bf16_t* __restrict__ Vt, bf16_t* __restrict__ O,
    bf16_t* __restrict__ Opart, float* __restrict__ ml)
{
  __shared__ bf16_t sK[2][64 * SKS];
  __shared__ bf16_t sV[2][64 * SKS];   // V^T: [d][kv]

  const int tid = threadIdx.x;
  const int w = tid >> 6, lane = tid & 63;
  const int l31 = lane & 31, hi = lane >> 5;

  const int id = blockIdx.x;
  const int cls = id >> 6;           // 0..23, longest-first
  const int bh = id & 63;
  const int qblk = d_qb[cls];
  const int hh = d_hh[cls];          // 0/1 split half, 2 whole
  const int ntf = 2 * qblk + 2;
  const int t0 = (hh == 1) ? (ntf >> 1) : 0;
  const int t1 = (hh == 0) ? (ntf >> 1) : ntf;

  const size_t hbase = (size_t)bh * SEQ * HDIM;
  const int b = bh >> 4, h = bh & 15;
  const int srow = tid >> 3, sslot = tid & 7;

  const int qbase = qblk * AQB + 32 * w;

  bf16x8 qf[4];
  #pragma unroll
  for (int kt = 0; kt < 4; ++kt)
    qf[kt] = *reinterpret_cast<const bf16x8*>(
        Q + hbase + (size_t)(qbase + l31) * HDIM + kt * 16 + hi * 8);
  asm volatile("s_waitcnt vmcnt(0)" ::: "memory");
  asm volatile("" : "+v"(qf[0]), "+v"(qf[1]), "+v"(qf[2]), "+v"(qf[3]));

  u32x4 kr[2], vr[2];
  auto issue = [&](int t) {
    const bf16_t* kp = Kb + hbase + (size_t)(t * AKV + srow) * HDIM + sslot * 8;
    const bf16_t* vp = Vt + hbase + (size_t)srow * SEQ + t * AKV + sslot * 8;
    asm volatile("global_load_dwordx4 %0, %1, off" : "=v"(kr[0]) : "v"(kp));
    asm volatile("global_load_dwordx4 %0, %1, off" : "=v"(kr[1]) : "v"(kp + 32 * HDIM));
    asm volatile("global_load_dwordx4 %0, %1, off" : "=v"(vr[0]) : "v"(vp));
    asm volatile("global_load_dwordx4 %0, %1, off" : "=v"(vr[1]) : "v"(vp + 32 * SEQ));
  };
  auto stage = [&](int nb) {
    #pragma unroll
    for (int cc = 0; cc < 2; ++cc) {
      int row = srow + 32 * cc;                  // kv row for K, d row for V^T
      *reinterpret_cast<u32x4*>(&sK[nb][row * SKS + ((sslot ^ (row >> 3)) << 3)]) = kr[cc];
      *reinterpret_cast<u32x4*>(&sV[nb][row * SKS + ((sslot ^ (row >> 3)) << 3)]) = vr[cc];
    }
  };

  float mrun = -1e30f, lrun = 0.f;
  f32x16 accO[2] = {};

  issue(t0);
  asm volatile("s_waitcnt vmcnt(0)" ::: "memory");
  stage(0);
  if (t0 + 1 < t1) issue(t0 + 1);
  asm volatile("s_waitcnt lgkmcnt(0)" ::: "memory");
  __builtin_amdgcn_s_barrier();
  asm volatile("" ::: "memory");

  int t = t0;
  if ((t1 - t0) & 1) {
    ATTN_BODY(0, t); ++t;
    for (; t < t1; t += 2) { ATTN_BODY(1, t); ATTN_BODY(0, t + 1); }
  } else {
    for (; t < t1; t += 2) { ATTN_BODY(0, t); ATTN_BODY(1, t + 1); }
  }

  lrun += __shfl_xor(lrun, 32);   // deferred cross-half sum merge

  // epilogue: transpose O^T -> rows via per-wave LDS region aliased onto sK
  bf16_t* sOw = &sK[0][0] + w * (32 * SKS);
  float inv = 1.f / lrun;
  #pragma unroll
  for (int dt = 0; dt < 2; ++dt)
    #pragma unroll
    for (int r = 0; r < 16; ++r) {
      int d = 32 * dt + (r & 3) + 8 * (r >> 2) + 4 * hi;
      sOw[l31 * SKS + (d ^ ((l31 >> 3) << 3))] = (bf16_t)(accO[dt][r] * inv);
    }
  if (hh == 2) {
    #pragma unroll
    for (int i = 0; i < 4; ++i) {
      int qr = 8 * i + (lane >> 3);
      int ch = lane & 7;
      bf16x8 vvv = *reinterpret_cast<const bf16x8*>(
          &sOw[qr * SKS + ((ch ^ (qr >> 3)) << 3)]);
      *reinterpret_cast<bf16x8*>(
          O + ((size_t)(b * SEQ + qbase + qr)) * DIMM + h * HDIM + ch * 8) = vvv;
    }
  } else {
    const int pb = ((qblk - 8) * 2 + hh) * 64 + bh;
    #pragma unroll
    for (int i = 0; i < 4; ++i) {
      int qr = 8 * i + (lane >> 3);
      int ch = lane & 7;
      bf16x8 vvv = *reinterpret_cast<const bf16x8*>(
          &sOw[qr * SKS + ((ch ^ (qr >> 3)) << 3)]);
      *reinterpret_cast<bf16x8*>(
          Opart + ((size_t)pb * 128 + 32 * w + qr) * 64 + ch * 8) = vvv;
    }
    if (hi == 0) {
      size_t mi = ((size_t)pb * 128 + 32 * w + l31) * 2;
      ml[mi] = mrun; ml[mi + 1] = lrun;
    }
  }
}

// ---- merge kernel: combine two normalized halves (log2-domain m) ----------
__global__ __launch_bounds__(256) void k_merge(
    const bf16_t* __restrict__ Opart, const float* __restrict__ ml,
    bf16_t* __restrict__ O)
{
  int blk = blockIdx.x;            // 0..511 : (qblk-8)*64 + bh
  int qi = blk >> 6;
  int bh = blk & 63;
  int b = bh >> 4, h = bh & 15;
  int qblk = qi + 8;
  int base0 = (qi * 2 + 0) * 64 + bh;
  int base1 = (qi * 2 + 1) * 64 + bh;
  int q = threadIdx.x >> 1;
  int d0 = (threadIdx.x & 1) * 32;

  float m0 = ml[((size_t)base0 * 128 + q) * 2], l0 = ml[((size_t)base0 * 128 + q) * 2 + 1];
  float m1 = ml[((size_t)base1 * 128 + q) * 2], l1 = ml[((size_t)base1 * 128 + q) * 2 + 1];
  float m = fmaxf(m0, m1);
  float w0 = fexp2(m0 - m) * l0;
  float w1 = fexp2(m1 - m) * l1;
  float inv = 1.f / (w0 + w1);
  w0 *= inv; w1 *= inv;

  const bf16_t* p0 = Opart + ((size_t)base0 * 128 + q) * 64 + d0;
  const bf16_t* p1 = Opart + ((size_t)base1 * 128 + q) * 64 + d0;
  bf16_t* po = O + ((size_t)(b * SEQ + qblk * 128 + q)) * DIMM + h * HDIM + d0;
  #pragma unroll
  for (int i = 0; i < 4; ++i) {
    bf16x8 a = *reinterpret_cast<const bf16x8*>(p0 + i * 8);
    bf16x8 c = *reinterpret_cast<const bf16x8*>(p1 + i * 8);
    bf16x8 o;
    #pragma unroll
    for (int j = 0; j < 8; ++j)
      o[j] = (bf16_t)(w0 * (float)a[j] + w1 * (float)c[j]);
    *reinterpret_cast<bf16x8*>(po + i * 8) = o;
  }
}

// ---------------------------------------------------------------------------
extern "C" void kernel_launch(void* const* d_in, const int* in_sizes, int n_in,
                              void* d_out, int out_size, void* d_ws, size_t ws_size,
                              hipStream_t stream) {
  const float* x     = (const float*)d_in[0];
  // d_in[1] = mask (causal tril) — structure hardcoded
  const float* qkv_w = (const float*)d_in[2];
  const float* qkv_b = (const float*)d_in[3];
  const float* out_w = (const float*)d_in[4];
  const float* out_b = (const float*)d_in[5];
  float* out = (float*)d_out;

  char* ws = (char*)d_ws;
  size_t off = 0;
  auto alloc = [&](size_t bytes) {
    char* p = ws + off;
    off += (bytes + 255) & ~(size_t)255;
    return (void*)p;
  };
  bf16_t* Xb    = (bf16_t*)alloc((size_t)MROWS * DIMM * 2);   // reused as Opart after gemm0
  bf16_t* WqkvT = (bf16_t*)alloc((size_t)3 * DIMM * DIMM * 2);
  bf16_t* WoutT = (bf16_t*)alloc((size_t)DIMM * DIMM * 2);
  bf16_t* Qh    = (bf16_t*)alloc((size_t)64 * SEQ * HDIM * 2);
  bf16_t* Kh    = (bf16_t*)alloc((size_t)64 * SEQ * HDIM * 2);
  bf16_t* Vth   = (bf16_t*)alloc((size_t)64 * HDIM * SEQ * 2);  // V^T [bh][d][t]
  bf16_t* AO    = (bf16_t*)alloc((size_t)MROWS * DIMM * 2);
  float*  cosT  = (float*)alloc((size_t)SEQ * 32 * 4);
  float*  sinT  = (float*)alloc((size_t)SEQ * 32 * 4);
  float*  mlbuf = (float*)alloc((size_t)16 * 64 * 128 * 2 * 4);  // 1 MB
  bf16_t* Opart = Xb;   // 16.7 MB partials alias Xb (dead after gemm0)

  k_convert<<<(MROWS * DIMM / 4 + 255) / 256, 256, 0, stream>>>(x, Xb, MROWS * DIMM / 4);
  k_transpose_convert<<<dim3(3 * DIMM / 32, DIMM / 32), dim3(32, 8), 0, stream>>>(qkv_w, WqkvT, DIMM, 3 * DIMM);
  k_transpose_convert<<<dim3(DIMM / 32, DIMM / 32), dim3(32, 8), 0, stream>>>(out_w, WoutT, DIMM, DIMM);
  k_rope_table<<<(SEQ * 32 + 255) / 256, 256, 0, stream>>>(cosT, sinT);

  k_gemm0<<<dim3(3 * DIMM / 256, MROWS / 256), 512, 0, stream>>>(
      Xb, WqkvT, qkv_b, Qh, Kh, Vth, cosT, sinT);

  k_attn<<<dim3(24 * 64), 256, 0, stream>>>(Qh, Kh, Vth, AO, Opart, mlbuf);

  k_merge<<<dim3(512), 256, 0, stream>>>(Opart, mlbuf, AO);

  k_gemm1<<<dim3(DIMM / 128, MROWS / 128), 256, 0, stream>>>(
      AO, WoutT, out_b, out, MROWS, DIMM, DIMM);
}